// Round 15
// baseline (215.487 us; speedup 1.0000x reference)
//
#include <hip/hip_runtime.h>
#include <hip/hip_bf16.h>
#include <cstdio>

typedef __bf16 bf16_t;
typedef __attribute__((ext_vector_type(8))) __bf16 bf16x8;
typedef __attribute__((ext_vector_type(4))) __bf16 bf16x4;
typedef __attribute__((ext_vector_type(2))) __bf16 bf16x2;
typedef __attribute__((ext_vector_type(4))) float f32x4;
typedef unsigned int u32;

#define SCALE 0.17677669529663687f   // 32^-0.5
#define LOG2E 1.44269504088896f
#define NWIN 294                     // 6*7*7
#define EXP2(x) __builtin_amdgcn_exp2f(x)

__device__ __forceinline__ void gload16(const void* g, void* l) {
  __builtin_amdgcn_global_load_lds(
      (const __attribute__((address_space(1))) void*)g,
      (__attribute__((address_space(3))) void*)l, 16, 0, 0);
}

__device__ __forceinline__ u32 pk2(float a, float b) {
  bf16x2 t = {(bf16_t)a, (bf16_t)b};
  return __builtin_bit_cast(u32, t);
}

// ---------------- K0a: convert weights to bf16 ----------------
__global__ void cvt_weights(const float* __restrict__ wq, const float* __restrict__ wo,
                            bf16_t* __restrict__ wqb, bf16_t* __restrict__ wob) {
  int t = blockIdx.x * 256 + threadIdx.x;
  const int nq4 = 768 * 256 / 4;
  if (t < nq4) {
    float4 v = ((const float4*)wq)[t];
    bf16x4 h = {(bf16_t)v.x, (bf16_t)v.y, (bf16_t)v.z, (bf16_t)v.w};
    ((bf16x4*)wqb)[t] = h;
  } else {
    int t2 = t - nq4;
    float4 v = ((const float4*)wo)[t2];
    bf16x4 h = {(bf16_t)v.x, (bf16_t)v.y, (bf16_t)v.z, (bf16_t)v.w};
    ((bf16x4*)wob)[t2] = h;
  }
}

// ---------------- K0b: bias, merged layout [h][jp][i][wv][lane][8] ----------------
__global__ void bias_kernel(const float* __restrict__ bt, const int* __restrict__ ridx,
                            bf16_t* __restrict__ biasf) {
  int t = blockIdx.x * 256 + threadIdx.x;
  if (t >= 8 * 10 * 5 * 4 * 64 * 8) return;   // 819200
  int r = t & 3, tt = (t >> 2) & 1, lane = (t >> 3) & 63;
  int rest = t >> 9;
  int wv = rest & 3; rest >>= 2;
  int i = rest % 5; rest /= 5;
  int jp = rest % 10; int hh = rest / 10;
  int s = wv + 4 * i;
  int q = s * 16 + (lane & 15);
  int k = (jp * 2 + tt) * 16 + 4 * (lane >> 4) + r;
  float v;
  if (k >= 294)                 v = -1e30f;
  else if (s >= 19 || q >= 294) v = 0.f;
  else                          v = bt[ridx[q * 294 + k] * 8 + hh] * LOG2E;
  biasf[t] = (bf16_t)v;
}

// ---------------- K1: QKV GEMM, slot-linear LDS (zero bank conflicts) ----------------
// Slot s (0..7) = rows s*16..s*16+15 x 32 cols, 1024B, lane l owns row (l&15), colgrp (l>>4).
// A: reg-staged fp32->bf16, ds_write_b128 at lane*16 (conflict-free). B: gload16 gather.
__global__ __launch_bounds__(256, 2)
void qkv_gemm(const float* __restrict__ x, const bf16_t* __restrict__ wqb,
              bf16_t* __restrict__ qkv) {
  __shared__ bf16_t As[2][4096];   // 8 slots * 512 elems
  __shared__ bf16_t Bs[2][4096];
  const int tid = threadIdx.x;
  const int lane = tid & 63;
  const int w = tid >> 6;
  const int p = (blockIdx.x & 7) * 441 + (blockIdx.x >> 3);   // 3528 = 8*441 (T1)
  const int mt = p / 6, nt = p % 6;
  const int m0 = mt * 128, n0 = nt * 128;

  // per-wave slot sources (slots 2w, 2w+1)
  const float* axsrc[2];
  const bf16_t* bsrc[2];
#pragma unroll
  for (int i = 0; i < 2; ++i) {
    int s = w * 2 + i;
    int R = m0 + s * 16 + (lane & 15);
    int b_ = R / 294, n = R - b_ * 294;
    int l = n / 49, pp = n - l * 49;
    int X = b_ >> 4, Y = b_ & 15;
    int srow = ((l * 16 + X) * 16 + Y) * 49 + pp;
    axsrc[i] = x + (size_t)srow * 256 + (lane >> 4) * 8;
    bsrc[i]  = wqb + (size_t)(n0 + s * 16 + (lane & 15)) * 256 + (lane >> 4) * 8;
  }

  const f32x4 zero4 = {0.f, 0.f, 0.f, 0.f};
  f32x4 acc[4][4];
#pragma unroll
  for (int i = 0; i < 4; ++i)
#pragma unroll
    for (int j = 0; j < 4; ++j) acc[i][j] = zero4;

  auto stageA = [&](int buf, int kk) {
    const int k0 = kk * 32;
#pragma unroll
    for (int i = 0; i < 2; ++i) {
      float4 v0 = *(const float4*)(axsrc[i] + k0);
      float4 v1 = *(const float4*)(axsrc[i] + k0 + 4);
      bf16x8 h = {(bf16_t)v0.x, (bf16_t)v0.y, (bf16_t)v0.z, (bf16_t)v0.w,
                  (bf16_t)v1.x, (bf16_t)v1.y, (bf16_t)v1.z, (bf16_t)v1.w};
      *(bf16x8*)&As[buf][(w * 2 + i) * 512 + lane * 8] = h;
    }
  };
  auto stageB = [&](int buf, int kk) {
    const int k0 = kk * 32;
#pragma unroll
    for (int i = 0; i < 2; ++i)
      gload16(bsrc[i] + k0, &Bs[buf][(w * 2 + i) * 512]);
  };
  auto compute = [&](int buf) {
    const int ma = (w >> 1) * 4, nb = (w & 1) * 4;
    bf16x8 a[4], bb[4];
#pragma unroll
    for (int i = 0; i < 4; ++i)
      a[i] = *(const bf16x8*)&As[buf][(ma + i) * 512 + lane * 8];
#pragma unroll
    for (int i = 0; i < 4; ++i)
      bb[i] = *(const bf16x8*)&Bs[buf][(nb + i) * 512 + lane * 8];
#pragma unroll
    for (int i = 0; i < 4; ++i)
#pragma unroll
      for (int j = 0; j < 4; ++j)
        acc[i][j] = __builtin_amdgcn_mfma_f32_16x16x32_bf16(a[i], bb[j], acc[i][j], 0, 0, 0);
  };

  stageA(0, 0); stageB(0, 0);
  __syncthreads();
#pragma unroll
  for (int kk = 0; kk < 8; ++kk) {
    int cur = kk & 1;
    if (kk < 7) { stageA(cur ^ 1, kk + 1); stageB(cur ^ 1, kk + 1); }
    compute(cur);
    __syncthreads();
  }

  const int mb = (w >> 1) * 64, nbc = (w & 1) * 64;
#pragma unroll
  for (int i = 0; i < 4; ++i)
#pragma unroll
    for (int r = 0; r < 4; ++r) {
      int row = m0 + mb + i * 16 + (lane >> 4) * 4 + r;
      size_t rb = (size_t)row * 768;
#pragma unroll
      for (int j = 0; j < 4; ++j) {
        int col = n0 + nbc + j * 16 + (lane & 15);
        float sc = (col < 256) ? (SCALE * LOG2E) : 1.0f;
        qkv[rb + col] = (bf16_t)(acc[i][j][r] * sc);
      }
    }
}

// ---------------- K2: attention (unchanged from R14) ----------------
__global__ __launch_bounds__(256, 2)
void attn_kernel(const bf16_t* __restrict__ qkv, const bf16_t* __restrict__ biasf,
                 bf16_t* __restrict__ aout) {
  __shared__ uint4 SMEM4[2496];   // 39936 B = K 19*1024 + V 20*1024
  char* KB = (char*)SMEM4;
  char* VB = KB + 19456;
  const int tid = threadIdx.x, lane = tid & 63, wv = tid >> 6;
  const int p = (blockIdx.x & 7) * 256 + (blockIdx.x >> 3);
  const int b_ = p >> 3, hh = p & 7;
  const size_t qbase = (size_t)b_ * 294 * 768;
  const uint4 z4 = {0u, 0u, 0u, 0u};

  if (tid < 64 && (tid & 15) >= 6) *(uint4*)(KB + 18 * 1024 + tid * 16) = z4;
  for (int idx = tid; idx < 832; idx += 256) {
    int k = 294 + (idx >> 5);
    int d = idx & 31;
    int kk = k & 31;
    int g, e;
    if (kk < 16) { g = kk >> 2; e = kk & 3; } else { g = (kk - 16) >> 2; e = 4 + (kk & 3); }
    *(unsigned short*)(VB + (18 + (d >= 16)) * 1024 + (g * 16 + (d & 15)) * 16 + e * 2) = 0;
  }

  for (int t = wv; t < 19; t += 4) {
    int krow = t * 16 + (lane & 15);
    if (krow < 294)
      gload16(qkv + qbase + (size_t)krow * 768 + 256 + hh * 32 + (lane >> 4) * 8,
              KB + t * 1024);
  }
  for (int idx = tid; idx < 1176; idx += 256) {   // 294 rows * 4 d-chunks
    int k = idx >> 2, q4 = idx & 3;
    uint4 v = *(const uint4*)(qkv + qbase + (size_t)k * 768 + 512 + hh * 32 + q4 * 8);
    const unsigned short* pv = (const unsigned short*)&v;
    int kk = k & 31, vb = (k >> 5) * 2;
    int g, e;
    if (kk < 16) { g = kk >> 2; e = kk & 3; } else { g = (kk - 16) >> 2; e = 4 + (kk & 3); }
    char* base0 = VB + vb * 1024 + (g * 16) * 16 + e * 2;
#pragma unroll
    for (int e2 = 0; e2 < 8; ++e2) {
      int d = q4 * 8 + e2;
      *(unsigned short*)(base0 + (d >= 16) * 1024 + (d & 15) * 16) = pv[e2];
    }
  }
  __syncthreads();

  const f32x4 zero4f = {0.f, 0.f, 0.f, 0.f};

  bf16x8 qf[5];
  f32x4 o0[5], o1[5];
  float rsum[5];
#pragma unroll
  for (int i = 0; i < 5; ++i) {
    int s = wv + 4 * i;
    qf[i] = __builtin_bit_cast(bf16x8, z4);
    o0[i] = zero4f; o1[i] = zero4f; rsum[i] = 0.f;
    if (s < 19) {
      int qrow = s * 16 + (lane & 15);
      if (qrow < 294)
        qf[i] = *(const bf16x8*)(qkv + qbase + (size_t)qrow * 768 + hh * 32 + (lane >> 4) * 8);
    }
  }
  const bf16_t* pb[5];
#pragma unroll
  for (int i = 0; i < 5; ++i)
    pb[i] = biasf + ((((size_t)hh * 10 + 0) * 5 + i) * 4 + wv) * 512 + lane * 8;

#pragma unroll 2
  for (int jp = 0; jp < 10; ++jp) {
    bf16x8 kf0 = *(const bf16x8*)(KB + (2 * jp) * 1024 + lane * 16);
    bf16x8 kf1 = __builtin_bit_cast(bf16x8, z4);
    if (jp < 9) kf1 = *(const bf16x8*)(KB + (2 * jp + 1) * 1024 + lane * 16);
    bf16x8 vf0 = *(const bf16x8*)(VB + (2 * jp + 0) * 1024 + lane * 16);
    bf16x8 vf1 = *(const bf16x8*)(VB + (2 * jp + 1) * 1024 + lane * 16);
#pragma unroll
    for (int i = 0; i < 5; ++i) {
      int s = wv + 4 * i;
      if (s >= 19) continue;   // wave-uniform
      bf16x8 bv = *(const bf16x8*)(pb[i]);
      f32x4 sa0 = __builtin_amdgcn_mfma_f32_16x16x32_bf16(kf0, qf[i], zero4f, 0, 0, 0);
      float p0 = EXP2(sa0[0] + (float)bv[0]);
      float p1 = EXP2(sa0[1] + (float)bv[1]);
      float p2 = EXP2(sa0[2] + (float)bv[2]);
      float p3 = EXP2(sa0[3] + (float)bv[3]);
      rsum[i] += (p0 + p1) + (p2 + p3);
      u32 lo0 = pk2(p0, p1), hi0 = pk2(p2, p3);
      u32 lo1 = 0u, hi1 = 0u;
      if (jp < 9) {
        f32x4 sa1 = __builtin_amdgcn_mfma_f32_16x16x32_bf16(kf1, qf[i], zero4f, 0, 0, 0);
        float q0 = EXP2(sa1[0] + (float)bv[4]);
        float q1 = EXP2(sa1[1] + (float)bv[5]);
        float q2 = EXP2(sa1[2] + (float)bv[6]);
        float q3 = EXP2(sa1[3] + (float)bv[7]);
        rsum[i] += (q0 + q1) + (q2 + q3);
        lo1 = pk2(q0, q1); hi1 = pk2(q2, q3);
      }
      uint4 paw = {lo0, hi0, lo1, hi1};
      bf16x8 pa = __builtin_bit_cast(bf16x8, paw);
      o0[i] = __builtin_amdgcn_mfma_f32_16x16x32_bf16(pa, vf0, o0[i], 0, 0, 0);
      o1[i] = __builtin_amdgcn_mfma_f32_16x16x32_bf16(pa, vf1, o1[i], 0, 0, 0);
    }
#pragma unroll
    for (int i = 0; i < 5; ++i) pb[i] += 10240;
  }

  const int h = lane >> 4;
#pragma unroll
  for (int i = 0; i < 5; ++i) {
    int s = wv + 4 * i;
    if (s >= 19) continue;
    float rs = rsum[i] + __shfl_xor(rsum[i], 16);
    rs += __shfl_xor(rs, 32);
    float inv = 1.f / rs;
#pragma unroll
    for (int r = 0; r < 4; ++r) {
      int ql = 4 * h + r;
      float iv = __shfl(inv, ql);
      int row = s * 16 + ql;
      if (row < 294) {
        size_t ob = ((size_t)b_ * 294 + row) * 256 + hh * 32 + (lane & 15);
        aout[ob]      = (bf16_t)(o0[i][r] * iv);
        aout[ob + 16] = (bf16_t)(o1[i][r] * iv);
      }
    }
  }
}

// ---------------- K3: output GEMM, slot-linear LDS (zero bank conflicts) ----------------
__global__ __launch_bounds__(256, 2)
void out_gemm(const bf16_t* __restrict__ aout, const bf16_t* __restrict__ wob,
              float* __restrict__ out) {
  __shared__ bf16_t As[2][4096];
  __shared__ bf16_t Bs[2][4096];
  const int tid = threadIdx.x, lane = tid & 63, w = tid >> 6;
  const int p = (blockIdx.x & 7) * 147 + (blockIdx.x >> 3);   // 1176 = 8*147 (T1)
  const int mt = p >> 1, nt = p & 1;
  const int m0 = mt * 128, n0 = nt * 128;

  const bf16_t* asrc[2];
  const bf16_t* bsrc[2];
#pragma unroll
  for (int i = 0; i < 2; ++i) {
    int s = w * 2 + i;
    asrc[i] = aout + (size_t)(m0 + s * 16 + (lane & 15)) * 256 + (lane >> 4) * 8;
    bsrc[i] = wob  + (size_t)(n0 + s * 16 + (lane & 15)) * 256 + (lane >> 4) * 8;
  }

  const f32x4 zero4 = {0.f, 0.f, 0.f, 0.f};
  f32x4 acc[4][4];
#pragma unroll
  for (int i = 0; i < 4; ++i)
#pragma unroll
    for (int j = 0; j < 4; ++j) acc[i][j] = zero4;

  auto stage = [&](int buf, int kk) {
    const int k0 = kk * 32;
#pragma unroll
    for (int i = 0; i < 2; ++i) {
      gload16(asrc[i] + k0, &As[buf][(w * 2 + i) * 512]);
      gload16(bsrc[i] + k0, &Bs[buf][(w * 2 + i) * 512]);
    }
  };
  auto compute = [&](int buf) {
    const int ma = (w >> 1) * 4, nb = (w & 1) * 4;
    bf16x8 a[4], bb[4];
#pragma unroll
    for (int i = 0; i < 4; ++i)
      a[i] = *(const bf16x8*)&As[buf][(ma + i) * 512 + lane * 8];
#pragma unroll
    for (int i = 0; i < 4; ++i)
      bb[i] = *(const bf16x8*)&Bs[buf][(nb + i) * 512 + lane * 8];
#pragma unroll
    for (int i = 0; i < 4; ++i)
#pragma unroll
      for (int j = 0; j < 4; ++j)
        acc[i][j] = __builtin_amdgcn_mfma_f32_16x16x32_bf16(a[i], bb[j], acc[i][j], 0, 0, 0);
  };

  stage(0, 0);
  __syncthreads();
#pragma unroll
  for (int kk = 0; kk < 8; ++kk) {
    int cur = kk & 1;
    if (kk < 7) stage(cur ^ 1, kk + 1);
    compute(cur);
    __syncthreads();
  }

  const int mb = (w >> 1) * 64, nbc = (w & 1) * 64;
#pragma unroll
  for (int i = 0; i < 4; ++i)
#pragma unroll
    for (int r = 0; r < 4; ++r) {
      int R = m0 + mb + i * 16 + (lane >> 4) * 4 + r;
      int b_ = R / 294, n = R - b_ * 294;
      int l = n / 49, pp = n - l * 49;
      int X = b_ >> 4, Y = b_ & 15;
      size_t drow = (size_t)(((l * 16 + X) * 16 + Y) * 49 + pp) * 256;
#pragma unroll
      for (int j = 0; j < 4; ++j) {
        int col = n0 + nbc + j * 16 + (lane & 15);
        out[drow + col] = acc[i][j][r];
      }
    }
}

// ---------------- launch ----------------
extern "C" void kernel_launch(void* const* d_in, const int* in_sizes, int n_in,
                              void* d_out, int out_size, void* d_ws, size_t ws_size,
                              hipStream_t stream) {
  const float* x   = (const float*)d_in[0];
  const float* wq  = (const float*)d_in[1];
  const float* wo  = (const float*)d_in[2];
  const float* bt  = (const float*)d_in[3];
  const int*   ri  = (const int*)d_in[4];
  float* out = (float*)d_out;

  char* ws = (char*)d_ws;
  bf16_t* qkv   = (bf16_t*)(ws);                  // 115,605,504 B
  bf16_t* aoutp = (bf16_t*)(ws + 115605504);      //  38,535,168 B
  bf16_t* wqb   = (bf16_t*)(ws + 154140672);      //     393,216 B
  bf16_t* wob   = (bf16_t*)(ws + 154533888);      //     131,072 B
  bf16_t* biasf = (bf16_t*)(ws + 154664960);      //   1,638,400 B -> total 156,303,360
  if (ws_size < 156303360ULL)
    fprintf(stderr, "WS TOO SMALL: %zu < 156303360\n", ws_size);

  hipLaunchKernelGGL(cvt_weights, dim3(256), dim3(256), 0, stream, wq, wo, wqb, wob);
  hipLaunchKernelGGL(bias_kernel, dim3(3200), dim3(256), 0, stream, bt, ri, biasf);
  hipLaunchKernelGGL(qkv_gemm, dim3(588 * 6), dim3(256), 0, stream, x, wqb, qkv);
  hipLaunchKernelGGL(attn_kernel, dim3(2048), dim3(256), 0, stream, qkv, biasf, aoutp);
  hipLaunchKernelGGL(out_gemm, dim3(588 * 2), dim3(256), 0, stream, aoutp, wob, out);
}

// Round 16
// 187.330 us; speedup vs baseline: 1.1503x; 1.1503x over previous
//
#include <hip/hip_runtime.h>
#include <hip/hip_bf16.h>
#include <cstdio>

typedef __bf16 bf16_t;
typedef __attribute__((ext_vector_type(8))) __bf16 bf16x8;
typedef __attribute__((ext_vector_type(4))) __bf16 bf16x4;
typedef __attribute__((ext_vector_type(2))) __bf16 bf16x2;
typedef __attribute__((ext_vector_type(4))) float f32x4;
typedef unsigned int u32;

#define SCALE 0.17677669529663687f   // 32^-0.5
#define LOG2E 1.44269504088896f
#define NWIN 294                     // 6*7*7
#define EXP2(x) __builtin_amdgcn_exp2f(x)

__device__ __forceinline__ void gload16(const void* g, void* l) {
  __builtin_amdgcn_global_load_lds(
      (const __attribute__((address_space(1))) void*)g,
      (__attribute__((address_space(3))) void*)l, 16, 0, 0);
}

__device__ __forceinline__ u32 pk2(float a, float b) {
  bf16x2 t = {(bf16_t)a, (bf16_t)b};
  return __builtin_bit_cast(u32, t);
}

// ---------------- K0a: convert weights to bf16 ----------------
__global__ void cvt_weights(const float* __restrict__ wq, const float* __restrict__ wo,
                            bf16_t* __restrict__ wqb, bf16_t* __restrict__ wob) {
  int t = blockIdx.x * 256 + threadIdx.x;
  const int nq4 = 768 * 256 / 4;
  if (t < nq4) {
    float4 v = ((const float4*)wq)[t];
    bf16x4 h = {(bf16_t)v.x, (bf16_t)v.y, (bf16_t)v.z, (bf16_t)v.w};
    ((bf16x4*)wqb)[t] = h;
  } else {
    int t2 = t - nq4;
    float4 v = ((const float4*)wo)[t2];
    bf16x4 h = {(bf16_t)v.x, (bf16_t)v.y, (bf16_t)v.z, (bf16_t)v.w};
    ((bf16x4*)wob)[t2] = h;
  }
}

// ---------------- K0b: bias, merged layout [h][jp][i][wv][lane][8] ----------------
__global__ void bias_kernel(const float* __restrict__ bt, const int* __restrict__ ridx,
                            bf16_t* __restrict__ biasf) {
  int t = blockIdx.x * 256 + threadIdx.x;
  if (t >= 8 * 10 * 5 * 4 * 64 * 8) return;   // 819200
  int r = t & 3, tt = (t >> 2) & 1, lane = (t >> 3) & 63;
  int rest = t >> 9;
  int wv = rest & 3; rest >>= 2;
  int i = rest % 5; rest /= 5;
  int jp = rest % 10; int hh = rest / 10;
  int s = wv + 4 * i;
  int q = s * 16 + (lane & 15);
  int k = (jp * 2 + tt) * 16 + 4 * (lane >> 4) + r;
  float v;
  if (k >= 294)                 v = -1e30f;
  else if (s >= 19 || q >= 294) v = 0.f;
  else                          v = bt[ridx[q * 294 + k] * 8 + hh] * LOG2E;
  biasf[t] = (bf16_t)v;
}

// ---------------- K1: QKV GEMM, BK=32 double-buffered (R14 exact — measured 98us) ----------------
__global__ __launch_bounds__(256, 2)
void qkv_gemm(const float* __restrict__ x, const bf16_t* __restrict__ wqb,
              bf16_t* __restrict__ qkv) {
  __shared__ bf16_t As[2][128][32];
  __shared__ bf16_t Bs[2][128][32];
  const int tid = threadIdx.x;
  const int lane = tid & 63;
  const int w = tid >> 6;
  const int p = (blockIdx.x & 7) * 441 + (blockIdx.x >> 3);   // 3528 = 8*441 (T1)
  const int mt = p / 6, nt = p % 6;
  const int m0 = mt * 128, n0 = nt * 128;

  const float* asrc[4];
#pragma unroll
  for (int i = 0; i < 4; ++i) {
    int R = m0 + i * 32 + (tid >> 3);
    int b_ = R / 294, n = R - b_ * 294;
    int l = n / 49, pp = n - l * 49;
    int X = b_ >> 4, Y = b_ & 15;
    int srow = ((l * 16 + X) * 16 + Y) * 49 + pp;
    asrc[i] = x + (size_t)srow * 256 + (tid & 7) * 4;
  }

  const f32x4 zero4 = {0.f, 0.f, 0.f, 0.f};
  f32x4 acc[4][4];
#pragma unroll
  for (int i = 0; i < 4; ++i)
#pragma unroll
    for (int j = 0; j < 4; ++j) acc[i][j] = zero4;

  auto stageA = [&](int buf, int kk) {
    const int k0 = kk * 32;
#pragma unroll
    for (int i = 0; i < 4; ++i) {
      float4 v = *(const float4*)(asrc[i] + k0);
      bf16x4 h = {(bf16_t)v.x, (bf16_t)v.y, (bf16_t)v.z, (bf16_t)v.w};
      *(bf16x4*)&As[buf][i * 32 + (tid >> 3)][(tid & 7) * 4] = h;
    }
  };
  auto stageB = [&](int buf, int kk) {
    const int k0 = kk * 32;
#pragma unroll
    for (int i = 0; i < 2; ++i) {
      int rb = w * 32 + i * 16;
      const bf16_t* g = wqb + (size_t)(n0 + rb + (lane >> 2)) * 256 + k0 + (lane & 3) * 8;
      gload16(g, &Bs[buf][rb][0]);
    }
  };
  auto compute = [&](int buf) {
    const int mb = (w >> 1) * 64, nb = (w & 1) * 64;
    bf16x8 a[4], bb[4];
#pragma unroll
    for (int i = 0; i < 4; ++i)
      a[i] = *(const bf16x8*)&As[buf][mb + i * 16 + (lane & 15)][(lane >> 4) * 8];
#pragma unroll
    for (int i = 0; i < 4; ++i)
      bb[i] = *(const bf16x8*)&Bs[buf][nb + i * 16 + (lane & 15)][(lane >> 4) * 8];
#pragma unroll
    for (int i = 0; i < 4; ++i)
#pragma unroll
      for (int j = 0; j < 4; ++j)
        acc[i][j] = __builtin_amdgcn_mfma_f32_16x16x32_bf16(a[i], bb[j], acc[i][j], 0, 0, 0);
  };

  stageA(0, 0); stageB(0, 0);
  __syncthreads();
#pragma unroll
  for (int kk = 0; kk < 8; ++kk) {
    int cur = kk & 1;
    if (kk < 7) { stageA(cur ^ 1, kk + 1); stageB(cur ^ 1, kk + 1); }
    compute(cur);
    __syncthreads();
  }

  const int mb = (w >> 1) * 64, nb = (w & 1) * 64;
#pragma unroll
  for (int i = 0; i < 4; ++i)
#pragma unroll
    for (int r = 0; r < 4; ++r) {
      int row = m0 + mb + i * 16 + (lane >> 4) * 4 + r;
      size_t rb = (size_t)row * 768;
#pragma unroll
      for (int j = 0; j < 4; ++j) {
        int col = n0 + nb + j * 16 + (lane & 15);
        float sc = (col < 256) ? (SCALE * LOG2E) : 1.0f;
        qkv[rb + col] = (bf16_t)(acc[i][j][r] * sc);
      }
    }
}

// ---------------- K2: attention (R14 exact) ----------------
__global__ __launch_bounds__(256, 2)
void attn_kernel(const bf16_t* __restrict__ qkv, const bf16_t* __restrict__ biasf,
                 bf16_t* __restrict__ aout) {
  __shared__ uint4 SMEM4[2496];   // 39936 B = K 19*1024 + V 20*1024
  char* KB = (char*)SMEM4;
  char* VB = KB + 19456;
  const int tid = threadIdx.x, lane = tid & 63, wv = tid >> 6;
  const int p = (blockIdx.x & 7) * 256 + (blockIdx.x >> 3);
  const int b_ = p >> 3, hh = p & 7;
  const size_t qbase = (size_t)b_ * 294 * 768;
  const uint4 z4 = {0u, 0u, 0u, 0u};

  if (tid < 64 && (tid & 15) >= 6) *(uint4*)(KB + 18 * 1024 + tid * 16) = z4;
  for (int idx = tid; idx < 832; idx += 256) {
    int k = 294 + (idx >> 5);
    int d = idx & 31;
    int kk = k & 31;
    int g, e;
    if (kk < 16) { g = kk >> 2; e = kk & 3; } else { g = (kk - 16) >> 2; e = 4 + (kk & 3); }
    *(unsigned short*)(VB + (18 + (d >= 16)) * 1024 + (g * 16 + (d & 15)) * 16 + e * 2) = 0;
  }

  for (int t = wv; t < 19; t += 4) {
    int krow = t * 16 + (lane & 15);
    if (krow < 294)
      gload16(qkv + qbase + (size_t)krow * 768 + 256 + hh * 32 + (lane >> 4) * 8,
              KB + t * 1024);
  }
  for (int idx = tid; idx < 1176; idx += 256) {   // 294 rows * 4 d-chunks
    int k = idx >> 2, q4 = idx & 3;
    uint4 v = *(const uint4*)(qkv + qbase + (size_t)k * 768 + 512 + hh * 32 + q4 * 8);
    const unsigned short* pv = (const unsigned short*)&v;
    int kk = k & 31, vb = (k >> 5) * 2;
    int g, e;
    if (kk < 16) { g = kk >> 2; e = kk & 3; } else { g = (kk - 16) >> 2; e = 4 + (kk & 3); }
    char* base0 = VB + vb * 1024 + (g * 16) * 16 + e * 2;
#pragma unroll
    for (int e2 = 0; e2 < 8; ++e2) {
      int d = q4 * 8 + e2;
      *(unsigned short*)(base0 + (d >= 16) * 1024 + (d & 15) * 16) = pv[e2];
    }
  }
  __syncthreads();

  const f32x4 zero4f = {0.f, 0.f, 0.f, 0.f};

  bf16x8 qf[5];
  f32x4 o0[5], o1[5];
  float rsum[5];
#pragma unroll
  for (int i = 0; i < 5; ++i) {
    int s = wv + 4 * i;
    qf[i] = __builtin_bit_cast(bf16x8, z4);
    o0[i] = zero4f; o1[i] = zero4f; rsum[i] = 0.f;
    if (s < 19) {
      int qrow = s * 16 + (lane & 15);
      if (qrow < 294)
        qf[i] = *(const bf16x8*)(qkv + qbase + (size_t)qrow * 768 + hh * 32 + (lane >> 4) * 8);
    }
  }
  const bf16_t* pb[5];
#pragma unroll
  for (int i = 0; i < 5; ++i)
    pb[i] = biasf + ((((size_t)hh * 10 + 0) * 5 + i) * 4 + wv) * 512 + lane * 8;

#pragma unroll 2
  for (int jp = 0; jp < 10; ++jp) {
    bf16x8 kf0 = *(const bf16x8*)(KB + (2 * jp) * 1024 + lane * 16);
    bf16x8 kf1 = __builtin_bit_cast(bf16x8, z4);
    if (jp < 9) kf1 = *(const bf16x8*)(KB + (2 * jp + 1) * 1024 + lane * 16);
    bf16x8 vf0 = *(const bf16x8*)(VB + (2 * jp + 0) * 1024 + lane * 16);
    bf16x8 vf1 = *(const bf16x8*)(VB + (2 * jp + 1) * 1024 + lane * 16);
#pragma unroll
    for (int i = 0; i < 5; ++i) {
      int s = wv + 4 * i;
      if (s >= 19) continue;   // wave-uniform
      bf16x8 bv = *(const bf16x8*)(pb[i]);   // 16B: tile0 r0..3 | tile1 r0..3
      f32x4 sa0 = __builtin_amdgcn_mfma_f32_16x16x32_bf16(kf0, qf[i], zero4f, 0, 0, 0);
      float p0 = EXP2(sa0[0] + (float)bv[0]);
      float p1 = EXP2(sa0[1] + (float)bv[1]);
      float p2 = EXP2(sa0[2] + (float)bv[2]);
      float p3 = EXP2(sa0[3] + (float)bv[3]);
      rsum[i] += (p0 + p1) + (p2 + p3);
      u32 lo0 = pk2(p0, p1), hi0 = pk2(p2, p3);
      u32 lo1 = 0u, hi1 = 0u;
      if (jp < 9) {
        f32x4 sa1 = __builtin_amdgcn_mfma_f32_16x16x32_bf16(kf1, qf[i], zero4f, 0, 0, 0);
        float q0 = EXP2(sa1[0] + (float)bv[4]);
        float q1 = EXP2(sa1[1] + (float)bv[5]);
        float q2 = EXP2(sa1[2] + (float)bv[6]);
        float q3 = EXP2(sa1[3] + (float)bv[7]);
        rsum[i] += (q0 + q1) + (q2 + q3);
        lo1 = pk2(q0, q1); hi1 = pk2(q2, q3);
      }
      uint4 paw = {lo0, hi0, lo1, hi1};
      bf16x8 pa = __builtin_bit_cast(bf16x8, paw);
      o0[i] = __builtin_amdgcn_mfma_f32_16x16x32_bf16(pa, vf0, o0[i], 0, 0, 0);
      o1[i] = __builtin_amdgcn_mfma_f32_16x16x32_bf16(pa, vf1, o1[i], 0, 0, 0);
    }
#pragma unroll
    for (int i = 0; i < 5; ++i) pb[i] += 10240;      // jp stride (elements)
  }

  const int h = lane >> 4;
#pragma unroll
  for (int i = 0; i < 5; ++i) {
    int s = wv + 4 * i;
    if (s >= 19) continue;
    float rs = rsum[i] + __shfl_xor(rsum[i], 16);
    rs += __shfl_xor(rs, 32);
    float inv = 1.f / rs;
#pragma unroll
    for (int r = 0; r < 4; ++r) {
      int ql = 4 * h + r;
      float iv = __shfl(inv, ql);
      int row = s * 16 + ql;
      if (row < 294) {
        size_t ob = ((size_t)b_ * 294 + row) * 256 + hh * 32 + (lane & 15);
        aout[ob]      = (bf16_t)(o0[i][r] * iv);
        aout[ob + 16] = (bf16_t)(o1[i][r] * iv);
      }
    }
  }
}

// ---------------- K3: output GEMM, BK=32 double-buffered (R14 exact) ----------------
__global__ __launch_bounds__(256, 2)
void out_gemm(const bf16_t* __restrict__ aout, const bf16_t* __restrict__ wob,
              float* __restrict__ out) {
  __shared__ bf16_t As[2][128][32];
  __shared__ bf16_t Bs[2][128][32];
  const int tid = threadIdx.x, lane = tid & 63, w = tid >> 6;
  const int p = (blockIdx.x & 7) * 147 + (blockIdx.x >> 3);   // 1176 = 8*147 (T1)
  const int mt = p >> 1, nt = p & 1;
  const int m0 = mt * 128, n0 = nt * 128;

  const f32x4 zero4 = {0.f, 0.f, 0.f, 0.f};
  f32x4 acc[4][4];
#pragma unroll
  for (int i = 0; i < 4; ++i)
#pragma unroll
    for (int j = 0; j < 4; ++j) acc[i][j] = zero4;

  auto stage = [&](int buf, int kk) {
    const int k0 = kk * 32;
#pragma unroll
    for (int i = 0; i < 2; ++i) {
      int rb = w * 32 + i * 16;
      gload16(aout + (size_t)(m0 + rb + (lane >> 2)) * 256 + k0 + (lane & 3) * 8,
              &As[buf][rb][0]);
      gload16(wob + (size_t)(n0 + rb + (lane >> 2)) * 256 + k0 + (lane & 3) * 8,
              &Bs[buf][rb][0]);
    }
  };
  auto compute = [&](int buf) {
    const int mb = (w >> 1) * 64, nb = (w & 1) * 64;
    bf16x8 a[4], bb[4];
#pragma unroll
    for (int i = 0; i < 4; ++i)
      a[i] = *(const bf16x8*)&As[buf][mb + i * 16 + (lane & 15)][(lane >> 4) * 8];
#pragma unroll
    for (int i = 0; i < 4; ++i)
      bb[i] = *(const bf16x8*)&Bs[buf][nb + i * 16 + (lane & 15)][(lane >> 4) * 8];
#pragma unroll
    for (int i = 0; i < 4; ++i)
#pragma unroll
      for (int j = 0; j < 4; ++j)
        acc[i][j] = __builtin_amdgcn_mfma_f32_16x16x32_bf16(a[i], bb[j], acc[i][j], 0, 0, 0);
  };

  stage(0, 0);
  __syncthreads();
#pragma unroll
  for (int kk = 0; kk < 8; ++kk) {
    int cur = kk & 1;
    if (kk < 7) stage(cur ^ 1, kk + 1);
    compute(cur);
    __syncthreads();
  }

  const int mb = (w >> 1) * 64, nb = (w & 1) * 64;
#pragma unroll
  for (int i = 0; i < 4; ++i)
#pragma unroll
    for (int r = 0; r < 4; ++r) {
      int R = m0 + mb + i * 16 + (lane >> 4) * 4 + r;
      int b_ = R / 294, n = R - b_ * 294;
      int l = n / 49, pp = n - l * 49;
      int X = b_ >> 4, Y = b_ & 15;
      size_t drow = (size_t)(((l * 16 + X) * 16 + Y) * 49 + pp) * 256;
#pragma unroll
      for (int j = 0; j < 4; ++j) {
        int col = n0 + nb + j * 16 + (lane & 15);
        out[drow + col] = acc[i][j][r];
      }
    }
}

// ---------------- launch ----------------
extern "C" void kernel_launch(void* const* d_in, const int* in_sizes, int n_in,
                              void* d_out, int out_size, void* d_ws, size_t ws_size,
                              hipStream_t stream) {
  const float* x   = (const float*)d_in[0];
  const float* wq  = (const float*)d_in[1];
  const float* wo  = (const float*)d_in[2];
  const float* bt  = (const float*)d_in[3];
  const int*   ri  = (const int*)d_in[4];
  float* out = (float*)d_out;

  char* ws = (char*)d_ws;
  bf16_t* qkv   = (bf16_t*)(ws);                  // 115,605,504 B
  bf16_t* aoutp = (bf16_t*)(ws + 115605504);      //  38,535,168 B
  bf16_t* wqb   = (bf16_t*)(ws + 154140672);      //     393,216 B
  bf16_t* wob   = (bf16_t*)(ws + 154533888);      //     131,072 B
  bf16_t* biasf = (bf16_t*)(ws + 154664960);      //   1,638,400 B -> total 156,303,360
  if (ws_size < 156303360ULL)
    fprintf(stderr, "WS TOO SMALL: %zu < 156303360\n", ws_size);

  hipLaunchKernelGGL(cvt_weights, dim3(256), dim3(256), 0, stream, wq, wo, wqb, wob);
  hipLaunchKernelGGL(bias_kernel, dim3(3200), dim3(256), 0, stream, bt, ri, biasf);
  hipLaunchKernelGGL(qkv_gemm, dim3(588 * 6), dim3(256), 0, stream, x, wqb, qkv);
  hipLaunchKernelGGL(attn_kernel, dim3(2048), dim3(256), 0, stream, qkv, biasf, aoutp);
  hipLaunchKernelGGL(out_gemm, dim3(588 * 2), dim3(256), 0, stream, aoutp, wob, out);
}